// Round 13
// baseline (304.524 us; speedup 1.0000x reference)
//
#include <hip/hip_runtime.h>
#include <math.h>

#define NB 8192
#define ND 128
#define NT 64        // number of 128-row tiles
#define NTRI 2080    // NT*(NT+1)/2 upper-triangle tile pairs
#define NPOSB 128    // per-label blocks (512 labels / 4 per block)
#define NBLK (NTRI + NPOSB)
#define NWORK 32     // row-finish worker blocks (last arrivals)
#define NLAB 512
#define MAXM 64

typedef unsigned short u16;
typedef unsigned int u32;
typedef __attribute__((ext_vector_type(8))) short bf16x8;
typedef __attribute__((ext_vector_type(4))) float f32x4;

#define G2 369.3299304675746f         // gamma * log2(e)
#define NEG_C (-23.083120654223414f)  // -G2/16
#define SENT (-1e30f)
#define LN2F 0.6931471805599453f
#define LOG2E 1.4426950408889634f

static __device__ __forceinline__ void gload16(const void* g, void* l) {
  __builtin_amdgcn_global_load_lds(
      (const __attribute__((address_space(1))) u32*)g,
      (__attribute__((address_space(3))) u32*)l, 16, 0, 0);
}

static __device__ __forceinline__ float fexp2(float x) {
  return __builtin_amdgcn_exp2f(x);    // v_exp_f32
}
static __device__ __forceinline__ float flog2(float x) {
  return __builtin_amdgcn_logf(x);     // v_log_f32 (base-2)
}

static __device__ __forceinline__ u16 f2bf(float f) {
  u32 u = __float_as_uint(f);
  u32 r = (u + 0x7FFF + ((u >> 16) & 1)) >> 16;   // RNE
  return (u16)r;
}

static __device__ __forceinline__ float wave_sum_f(float v) {
  #pragma unroll
  for (int off = 1; off < 64; off <<= 1) v += __shfl_xor(v, off);
  return v;
}

// ---- k1: normalize rows + cast to bf16; reset arrival counters ------------
__global__ __launch_bounds__(512) void k_prep(const float* __restrict__ emb,
                                              u16* __restrict__ e,
                                              int* __restrict__ counters) {
  if (blockIdx.x == 0 && threadIdx.x < 2) counters[threadIdx.x] = 0;
  const int l = threadIdx.x & 63;
  const int w = threadIdx.x >> 6;
  const int row = blockIdx.x * 8 + w;
  const float2 v = reinterpret_cast<const float2*>(emb)[(size_t)row * 64 + l];
  float ss = wave_sum_f(v.x * v.x + v.y * v.y);
  const float inv = 1.0f / fmaxf(sqrtf(ss), 1e-12f);
  ushort2 o;
  o.x = f2bf(v.x * inv);
  o.y = f2bf(v.y * inv);
  reinterpret_cast<ushort2*>(e)[(size_t)row * 64 + l] = o;
}

// ---- k2: triangle tiles | per-label pos | fused row-finish tail -----------
// amdgpu_waves_per_eu(2,4): cap occupancy target at 4 waves/EU so the
// allocator budgets >=128 VGPRs. Without it the backend targeted 8 waves/EU
// (64 VGPR) and spilled the hot loop to scratch (rounds 10-12: ~300us,
// WRITE_SIZE 16.7MB, VALUBusy 4%).
__global__ __launch_bounds__(256)
__attribute__((amdgpu_waves_per_eu(2, 4)))
void k_all(const u16* __restrict__ e,
           const int* __restrict__ labels,
           float* __restrict__ part,
           float* __restrict__ poscorr,
           float* __restrict__ bsum,
           int* __restrict__ counters,
           float* __restrict__ out) {
  __shared__ __align__(16) char S[33792];   // B tiles / labels+memL / colbuf
  __shared__ int sprev;
  __shared__ int lastf;
  __shared__ float svals[4], scnts[4];

  const int bid = blockIdx.x;
  const int tid = threadIdx.x;
  const int l = tid & 63;
  const int w = tid >> 6;
  const int lr_ = l & 15;
  const int lg = l >> 4;

  if (bid < NTRI) {
    // ================= triangle sim tiles (round-9 verbatim) ===============
    int ti = (int)((129.0f - sqrtf(16641.0f - 8.0f * (float)bid)) * 0.5f);
    if (ti > NT - 1) ti = NT - 1;
    if (ti < 0) ti = 0;
    #define PRE(t) ((t) * NT - ((t) * ((t) - 1)) / 2)
    while (PRE(ti + 1) <= bid) ++ti;
    while (PRE(ti) > bid) --ti;
    const int tj = ti + (bid - PRE(ti));
    #undef PRE
    const int row0 = ti * 128;
    const int col0 = tj * 128;
    const bool diag = (ti == tj);
    char* Bh[2] = { S, S + 16384 };

    // A fragments in registers: rows row0 + w*32 + m*16 + lr_
    bf16x8 af[2][4];
    #pragma unroll
    for (int m = 0; m < 2; ++m)
      #pragma unroll
      for (int ks = 0; ks < 4; ++ks)
        af[m][ks] = *(const bf16x8*)(e + (size_t)(row0 + w * 32 + m * 16 + lr_) * ND +
                                     ks * 32 + lg * 8);

    // stage half 0 (swizzled source, linear LDS dest)
    #pragma unroll
    for (int i = 0; i < 4; ++i) {
      const int rr = w * 16 + i * 4 + lg;
      gload16(e + (size_t)(col0 + rr) * ND + (lr_ ^ (rr & 15)) * 8,
              Bh[0] + w * 4096 + i * 1024);
    }

    float sn[8], colp[8];
    #pragma unroll
    for (int q = 0; q < 8; ++q) { sn[q] = 0.f; colp[q] = 0.f; }

    __syncthreads();   // half 0 landed

    // stage half 1; lands during half-0 compute
    #pragma unroll
    for (int i = 0; i < 4; ++i) {
      const int rr = w * 16 + i * 4 + lg;
      gload16(e + (size_t)(col0 + 64 + rr) * ND + (lr_ ^ (rr & 15)) * 8,
              Bh[1] + w * 4096 + i * 1024);
    }

    #pragma unroll
    for (int h = 0; h < 2; ++h) {
      f32x4 acc[2][4];
      #pragma unroll
      for (int m = 0; m < 2; ++m)
        #pragma unroll
        for (int n = 0; n < 4; ++n)
          #pragma unroll
          for (int q = 0; q < 4; ++q) acc[m][n][q] = 0.f;

      #pragma unroll
      for (int ks = 0; ks < 4; ++ks) {
        const int kslot = (ks * 4 + lg) ^ lr_;   // read-side swizzle
        bf16x8 bfr[4];
        #pragma unroll
        for (int n = 0; n < 4; ++n)
          bfr[n] = *(const bf16x8*)(Bh[h] + (n * 16 + lr_) * 256 + kslot * 16);
        #pragma unroll
        for (int m = 0; m < 2; ++m)
          #pragma unroll
          for (int n = 0; n < 4; ++n)
            acc[m][n] = __builtin_amdgcn_mfma_f32_16x16x32_bf16(af[m][ks], bfr[n],
                                                                acc[m][n], 0, 0, 0);
      }

      // epilogue: ev feeds row sums and (by symmetry) column sums
      #pragma unroll
      for (int m = 0; m < 2; ++m) {
        #pragma unroll
        for (int n = 0; n < 4; ++n) {
          const bool dmn = diag && (w * 32 + m * 16 == h * 64 + n * 16);
          float scc = 0.f;
          #pragma unroll
          for (int j = 0; j < 4; ++j) {
            const float sv = acc[m][n][j];
            float xn = fmaf(sv * sv, G2, NEG_C);
            xn = (sv > -0.25f) ? xn : 0.f;
            if (dmn) xn = (lr_ == lg * 4 + j) ? SENT : xn;  // drop true diagonal
            const float ev = fexp2(xn);
            sn[m * 4 + j] += ev;
            scc += ev;
          }
          colp[h * 4 + n] += scc;
        }
      }
      if (h == 0) __syncthreads();   // half 1 landed
    }

    // row sums: reduce over 16 column-lanes, write slot tj
    #pragma unroll
    for (int q = 0; q < 8; ++q) {
      #pragma unroll
      for (int off = 1; off < 16; off <<= 1) sn[q] += __shfl_xor(sn[q], off);
    }
    if (lr_ == 0) {
      #pragma unroll
      for (int m = 0; m < 2; ++m)
        #pragma unroll
        for (int j = 0; j < 4; ++j) {
          const int row = row0 + w * 32 + m * 16 + lg * 4 + j;
          part[(size_t)row * NT + tj] = sn[m * 4 + j];
        }
    }

    // column sums (non-diag): reduce lg groups, cross-wave via LDS
    if (!diag) {
      #pragma unroll
      for (int q = 0; q < 8; ++q) {
        colp[q] += __shfl_xor(colp[q], 16);
        colp[q] += __shfl_xor(colp[q], 32);
      }
      __syncthreads();                   // all MFMA LDS reads done
      float* colbuf = (float*)S;
      if (l < 16) {
        #pragma unroll
        for (int q = 0; q < 8; ++q)
          colbuf[w * 128 + (q >> 2) * 64 + (q & 3) * 16 + lr_] = colp[q];
      }
      __syncthreads();
      if (tid < 128) {
        const float cs_ = colbuf[tid] + colbuf[128 + tid] +
                          colbuf[256 + tid] + colbuf[384 + tid];
        part[(size_t)(col0 + tid) * NT + ti] = cs_;
      }
    }
  } else {
    // ================= per-label positives + same-label correction =========
    int* lab = (int*)S;                        // 8192 ints = 32 KB
    for (int i = tid; i < NB / 4; i += 256)
      ((int4*)lab)[i] = ((const int4*)labels)[i];
    __syncthreads();

    const int L = (bid - NTRI) * 4 + w;        // one wave per label
    int* memL = (int*)(S + 32768) + w * MAXM;

    // build ordered member list via ballot rounds (ascending index order)
    int cnt = 0;
    for (int base = 0; base < NB; base += 64) {
      const int lv = lab[base + l];
      const unsigned long long mk = __ballot(lv == L);
      if (lv == L) {
        const int pos = __popcll(mk & ((1ull << l) - 1));
        if (cnt + pos < MAXM) memL[cnt + pos] = base + l;
      }
      cnt += __popcll(mk);
    }
    int c = cnt > MAXM ? MAXM : cnt;
    __syncthreads();   // memL visible across lanes of each wave

    const int nt = (c + 15) >> 4;
    for (int rb = 0; rb < nt; ++rb) {
      const int ri = rb * 16 + lr_;
      bf16x8 af[4];
      if (ri < c) {
        const u16* src = e + (size_t)memL[ri] * ND;
        #pragma unroll
        for (int ks = 0; ks < 4; ++ks)
          af[ks] = *(const bf16x8*)(src + ks * 32 + lg * 8);
      } else {
        #pragma unroll
        for (int ks = 0; ks < 4; ++ks) af[ks] = (bf16x8)0;
      }
      float corr[4], mp[4], sp[4];
      #pragma unroll
      for (int r = 0; r < 4; ++r) { corr[r] = 0.f; mp[r] = SENT; sp[r] = 0.f; }

      for (int cb = 0; cb < nt; ++cb) {
        const int ci = cb * 16 + lr_;
        bf16x8 bfr[4];
        if (ci < c) {
          const u16* src = e + (size_t)memL[ci] * ND;
          #pragma unroll
          for (int ks = 0; ks < 4; ++ks)
            bfr[ks] = *(const bf16x8*)(src + ks * 32 + lg * 8);
        } else {
          #pragma unroll
          for (int ks = 0; ks < 4; ++ks) bfr[ks] = (bf16x8)0;
        }
        f32x4 acc;
        #pragma unroll
        for (int r = 0; r < 4; ++r) acc[r] = 0.f;
        #pragma unroll
        for (int ks = 0; ks < 4; ++ks)
          acc = __builtin_amdgcn_mfma_f32_16x16x32_bf16(af[ks], bfr[ks], acc, 0, 0, 0);

        #pragma unroll
        for (int r = 0; r < 4; ++r) {
          const int R = rb * 16 + lg * 4 + r;
          const int Cj = cb * 16 + lr_;
          const bool ok = (R < c) && (Cj < c) && (R != Cj);
          const float sv = acc[r];
          float xn = fmaf(sv * sv, G2, NEG_C);
          xn = (sv > -0.25f) ? xn : 0.f;
          corr[r] += ok ? fexp2(xn) : 0.f;
          if (ok) {
            const float t1 = 1.25f - sv;
            const float xp = G2 * fmaxf(t1, 0.f) * (t1 - 0.5f);
            if (xp > mp[r]) { sp[r] = sp[r] * fexp2(mp[r] - xp) + 1.f; mp[r] = xp; }
            else sp[r] += fexp2(xp - mp[r]);
          }
        }
      }
      #pragma unroll
      for (int r = 0; r < 4; ++r) {
        #pragma unroll
        for (int off = 1; off < 16; off <<= 1) {
          corr[r] += __shfl_xor(corr[r], off);
          const float m2 = __shfl_xor(mp[r], off), s2 = __shfl_xor(sp[r], off);
          const float M = fmaxf(mp[r], m2);
          const float t1 = sp[r] * fexp2(mp[r] - M);  // exp2(-1e30)=0 for empties
          const float t2 = s2 * fexp2(m2 - M);
          mp[r] = M; sp[r] = t1 + t2;
        }
      }
      if (lr_ == 0) {
        #pragma unroll
        for (int r = 0; r < 4; ++r) {
          const int R = rb * 16 + lg * 4 + r;
          if (R < c) {
            float* o = poscorr + (size_t)memL[R] * 4;
            o[0] = mp[r]; o[1] = sp[r]; o[2] = corr[r]; o[3] = (float)(c - 1);
          }
        }
      }
    }
  }

  // ================= arrival tail: last NWORK blocks finish the rows =======
  __syncthreads();
  __threadfence();                              // release part/poscorr writes
  if (tid == 0) sprev = atomicAdd(&counters[0], 1);
  __syncthreads();
  const int myPos = sprev;
  if (myPos < NBLK - NWORK) return;

  const int chunk = myPos - (NBLK - NWORK);
  if (tid == 0) {
    while (__hip_atomic_load(&counters[0], __ATOMIC_ACQUIRE,
                             __HIP_MEMORY_SCOPE_AGENT) < NBLK)
      __builtin_amdgcn_s_sleep(8);
  }
  __syncthreads();
  __threadfence();

  {
    const int row = chunk * 256 + tid;
    float sn = 0.f;
    const float* pp = part + (size_t)row * NT;
    #pragma unroll 8
    for (int q = 0; q < NT; ++q)
      sn += __hip_atomic_load(pp + q, __ATOMIC_RELAXED, __HIP_MEMORY_SCOPE_AGENT);
    const float* pcp = poscorr + (size_t)row * 4;
    float pc[4];
    #pragma unroll
    for (int q = 0; q < 4; ++q)
      pc[q] = __hip_atomic_load(pcp + q, __ATOMIC_RELAXED, __HIP_MEMORY_SCOPE_AGENT);
    const int npi = (int)(pc[3] + 0.5f);
    const bool valid = (npi > 0) && (npi < NB - 1);
    float val = 0.f;
    if (valid) {
      const float snn = fmaxf(sn - pc[2], 1e-30f);
      const float lp = LN2F * (pc[0] + flog2(pc[1]));
      const float ln_ = LN2F * flog2(snn);
      const float x = lp + ln_;
      // softplus(x) = max(x,0) + ln(1 + 2^(-|x|*log2e)); call-free
      val = fmaxf(x, 0.f) + LN2F * flog2(1.0f + fexp2(-fabsf(x) * LOG2E));
    }
    float cntv = valid ? 1.f : 0.f;
    val = wave_sum_f(val);
    cntv = wave_sum_f(cntv);
    if (l == 0) { svals[w] = val; scnts[w] = cntv; }
    __syncthreads();
    if (tid == 0) {
      bsum[chunk * 2 + 0] = svals[0] + svals[1] + svals[2] + svals[3];
      bsum[chunk * 2 + 1] = scnts[0] + scnts[1] + scnts[2] + scnts[3];
      __threadfence();
      lastf = (atomicAdd(&counters[1], 1) == NWORK - 1);
    }
    __syncthreads();
    if (lastf && w == 0) {
      __threadfence();
      float s = 0.f, c = 0.f;
      if (l < NWORK) {
        s = __hip_atomic_load(bsum + l * 2, __ATOMIC_RELAXED, __HIP_MEMORY_SCOPE_AGENT);
        c = __hip_atomic_load(bsum + l * 2 + 1, __ATOMIC_RELAXED, __HIP_MEMORY_SCOPE_AGENT);
      }
      s = wave_sum_f(s);
      c = wave_sum_f(c);
      if (l == 0) out[0] = s / fmaxf(c, 1.f);
    }
  }
}

extern "C" void kernel_launch(void* const* d_in, const int* in_sizes, int n_in,
                              void* d_out, int out_size, void* d_ws, size_t ws_size,
                              hipStream_t stream) {
  const float* emb = (const float*)d_in[0];
  const int* labels = (const int*)d_in[1];
  float* out = (float*)d_out;
  char* ws = (char*)d_ws;

  float* part    = (float*)(ws + 0);         // 8192*64*4  = 2097152
  float* poscorr = (float*)(ws + 2097152);   // 8192*4*4   = 131072
  u16*   ebf     = (u16*)  (ws + 2228224);   // 8192*128*2 = 2097152
  float* bsum    = (float*)(ws + 4325376);   // 256 B
  int*   counters= (int*)  (ws + 4325632);   // 8 B

  k_prep<<<NB / 8, 512, 0, stream>>>(emb, ebf, counters);
  k_all<<<NBLK, 256, 0, stream>>>(ebf, labels, part, poscorr, bsum, counters, out);
}

// Round 14
// 46.861 us; speedup vs baseline: 6.4984x; 6.4984x over previous
//
#include <hip/hip_runtime.h>
#include <math.h>

#define NB 8192
#define ND 128
#define NT 64        // number of 128-row tiles
#define NTRI 2080    // NT*(NT+1)/2 upper-triangle tile pairs
#define NLAB 512
#define MAXM 64

typedef unsigned short u16;
typedef unsigned int u32;
typedef __attribute__((ext_vector_type(8))) short bf16x8;
typedef __attribute__((ext_vector_type(4))) float f32x4;

#define G2 369.3299304675746f         // gamma * log2(e)
#define NEG_C (-23.083120654223414f)  // -G2/16
#define SENT (-1e30f)
#define LN2F 0.6931471805599453f

static __device__ __forceinline__ void gload16(const void* g, void* l) {
  __builtin_amdgcn_global_load_lds(
      (const __attribute__((address_space(1))) u32*)g,
      (__attribute__((address_space(3))) u32*)l, 16, 0, 0);
}

static __device__ __forceinline__ float fexp2(float x) {
  return __builtin_amdgcn_exp2f(x);
}

static __device__ __forceinline__ u16 f2bf(float f) {
  u32 u = __float_as_uint(f);
  u32 r = (u + 0x7FFF + ((u >> 16) & 1)) >> 16;   // RNE
  return (u16)r;
}

static __device__ __forceinline__ float wave_sum_f(float v) {
  #pragma unroll
  for (int off = 1; off < 64; off <<= 1) v += __shfl_xor(v, off);
  return v;
}

// ---- k1: normalize rows + cast to bf16; reset arrival counter -------------
__global__ __launch_bounds__(512) void k_prep(const float* __restrict__ emb,
                                              u16* __restrict__ e,
                                              int* __restrict__ counters) {
  if (blockIdx.x == 0 && threadIdx.x < 2) counters[threadIdx.x] = 0;
  const int l = threadIdx.x & 63;
  const int w = threadIdx.x >> 6;
  const int row = blockIdx.x * 8 + w;
  const float2 v = reinterpret_cast<const float2*>(emb)[(size_t)row * 64 + l];
  float ss = wave_sum_f(v.x * v.x + v.y * v.y);
  const float inv = 1.0f / fmaxf(sqrtf(ss), 1e-12f);
  ushort2 o;
  o.x = f2bf(v.x * inv);
  o.y = f2bf(v.y * inv);
  reinterpret_cast<ushort2*>(e)[(size_t)row * 64 + l] = o;
}

// ---- k2: blocks 0..NTRI-1 = upper-triangle sim tiles; rest = per-label pos
// part layout TRANSPOSED vs round 9: part[slot][NB] -> coalesced writes
// (block's 128 row-sums land in one contiguous 512B region) and coalesced
// k_rowsfinal reads. Round 9's [row][NT] layout cost 16.7MB of 32B-sector
// write amplification for 2.2MB of payload.
__global__ __launch_bounds__(256, 3) void k_mainpos(const u16* __restrict__ e,
                                                    const int* __restrict__ labels,
                                                    float* __restrict__ part,
                                                    float* __restrict__ poscorr) {
  __shared__ __align__(16) char S[33792];   // 33 KB: B tiles / labels+memL
  const int bid = blockIdx.x;
  const int tid = threadIdx.x;
  const int l = tid & 63;
  const int w = tid >> 6;
  const int lr_ = l & 15;
  const int lg = l >> 4;

  if (bid < NTRI) {
    // ================= triangle sim tiles =======
    int ti = (int)((129.0f - sqrtf(16641.0f - 8.0f * (float)bid)) * 0.5f);
    if (ti > NT - 1) ti = NT - 1;
    if (ti < 0) ti = 0;
    #define PRE(t) ((t) * NT - ((t) * ((t) - 1)) / 2)
    while (PRE(ti + 1) <= bid) ++ti;
    while (PRE(ti) > bid) --ti;
    const int tj = ti + (bid - PRE(ti));
    #undef PRE
    const int row0 = ti * 128;
    const int col0 = tj * 128;
    const bool diag = (ti == tj);
    char* Bh[2] = { S, S + 16384 };

    // A fragments in registers: rows row0 + w*32 + m*16 + lr_
    bf16x8 af[2][4];
    #pragma unroll
    for (int m = 0; m < 2; ++m)
      #pragma unroll
      for (int ks = 0; ks < 4; ++ks)
        af[m][ks] = *(const bf16x8*)(e + (size_t)(row0 + w * 32 + m * 16 + lr_) * ND +
                                     ks * 32 + lg * 8);

    // stage half 0 (swizzled source, linear LDS dest)
    #pragma unroll
    for (int i = 0; i < 4; ++i) {
      const int rr = w * 16 + i * 4 + lg;
      gload16(e + (size_t)(col0 + rr) * ND + (lr_ ^ (rr & 15)) * 8,
              Bh[0] + w * 4096 + i * 1024);
    }

    float sn[8], colp[8];
    #pragma unroll
    for (int q = 0; q < 8; ++q) { sn[q] = 0.f; colp[q] = 0.f; }

    __syncthreads();   // half 0 landed

    // stage half 1; lands during half-0 compute
    #pragma unroll
    for (int i = 0; i < 4; ++i) {
      const int rr = w * 16 + i * 4 + lg;
      gload16(e + (size_t)(col0 + 64 + rr) * ND + (lr_ ^ (rr & 15)) * 8,
              Bh[1] + w * 4096 + i * 1024);
    }

    #pragma unroll
    for (int h = 0; h < 2; ++h) {
      f32x4 acc[2][4];
      #pragma unroll
      for (int m = 0; m < 2; ++m)
        #pragma unroll
        for (int n = 0; n < 4; ++n)
          #pragma unroll
          for (int q = 0; q < 4; ++q) acc[m][n][q] = 0.f;

      #pragma unroll
      for (int ks = 0; ks < 4; ++ks) {
        const int kslot = (ks * 4 + lg) ^ lr_;   // read-side swizzle
        bf16x8 bfr[4];
        #pragma unroll
        for (int n = 0; n < 4; ++n)
          bfr[n] = *(const bf16x8*)(Bh[h] + (n * 16 + lr_) * 256 + kslot * 16);
        #pragma unroll
        for (int m = 0; m < 2; ++m)
          #pragma unroll
          for (int n = 0; n < 4; ++n)
            acc[m][n] = __builtin_amdgcn_mfma_f32_16x16x32_bf16(af[m][ks], bfr[n],
                                                                acc[m][n], 0, 0, 0);
      }

      // epilogue: ev feeds row sums and (by symmetry) column sums
      #pragma unroll
      for (int m = 0; m < 2; ++m) {
        #pragma unroll
        for (int n = 0; n < 4; ++n) {
          const bool dmn = diag && (w * 32 + m * 16 == h * 64 + n * 16);
          float scc = 0.f;
          #pragma unroll
          for (int j = 0; j < 4; ++j) {
            const float sv = acc[m][n][j];
            float xn = fmaf(sv * sv, G2, NEG_C);
            xn = (sv > -0.25f) ? xn : 0.f;
            if (dmn) xn = (lr_ == lg * 4 + j) ? SENT : xn;  // drop true diagonal
            const float ev = fexp2(xn);
            sn[m * 4 + j] += ev;
            scc += ev;
          }
          colp[h * 4 + n] += scc;
        }
      }
      if (h == 0) __syncthreads();   // half 1 landed
    }

    // row sums: reduce over 16 column-lanes, write slot tj (coalesced region)
    #pragma unroll
    for (int q = 0; q < 8; ++q) {
      #pragma unroll
      for (int off = 1; off < 16; off <<= 1) sn[q] += __shfl_xor(sn[q], off);
    }
    if (lr_ == 0) {
      #pragma unroll
      for (int m = 0; m < 2; ++m)
        #pragma unroll
        for (int j = 0; j < 4; ++j) {
          const int row = row0 + w * 32 + m * 16 + lg * 4 + j;
          part[(size_t)tj * NB + row] = sn[m * 4 + j];
        }
    }

    // column sums (non-diag): reduce lg groups, cross-wave via LDS
    if (!diag) {
      #pragma unroll
      for (int q = 0; q < 8; ++q) {
        colp[q] += __shfl_xor(colp[q], 16);
        colp[q] += __shfl_xor(colp[q], 32);
      }
      __syncthreads();                   // all MFMA LDS reads done
      float* colbuf = (float*)S;
      if (l < 16) {
        #pragma unroll
        for (int q = 0; q < 8; ++q)
          colbuf[w * 128 + (q >> 2) * 64 + (q & 3) * 16 + lr_] = colp[q];
      }
      __syncthreads();
      if (tid < 128) {
        const float cs_ = colbuf[tid] + colbuf[128 + tid] +
                          colbuf[256 + tid] + colbuf[384 + tid];
        part[(size_t)ti * NB + col0 + tid] = cs_;   // 128 consecutive floats
      }
    }
  } else {
    // ================= per-label positives + same-label correction =========
    int* lab = (int*)S;                        // 8192 ints = 32 KB
    for (int i = tid; i < NB / 4; i += 256)
      ((int4*)lab)[i] = ((const int4*)labels)[i];
    __syncthreads();

    const int L = (bid - NTRI) * 4 + w;        // one wave per label
    int* memL = (int*)(S + 32768) + w * MAXM;

    // build ordered member list via ballot rounds (ascending index order)
    int cnt = 0;
    for (int base = 0; base < NB; base += 64) {
      const int lv = lab[base + l];
      const unsigned long long mk = __ballot(lv == L);
      if (lv == L) {
        const int pos = __popcll(mk & ((1ull << l) - 1));
        if (cnt + pos < MAXM) memL[cnt + pos] = base + l;
      }
      cnt += __popcll(mk);
    }
    int c = cnt > MAXM ? MAXM : cnt;
    __syncthreads();   // memL visible across lanes of each wave

    const int nt = (c + 15) >> 4;
    for (int rb = 0; rb < nt; ++rb) {
      const int ri = rb * 16 + lr_;
      bf16x8 af[4];
      if (ri < c) {
        const u16* src = e + (size_t)memL[ri] * ND;
        #pragma unroll
        for (int ks = 0; ks < 4; ++ks)
          af[ks] = *(const bf16x8*)(src + ks * 32 + lg * 8);
      } else {
        #pragma unroll
        for (int ks = 0; ks < 4; ++ks) af[ks] = (bf16x8)0;
      }
      float corr[4], mp[4], sp[4];
      #pragma unroll
      for (int r = 0; r < 4; ++r) { corr[r] = 0.f; mp[r] = SENT; sp[r] = 0.f; }

      for (int cb = 0; cb < nt; ++cb) {
        const int ci = cb * 16 + lr_;
        bf16x8 bfr[4];
        if (ci < c) {
          const u16* src = e + (size_t)memL[ci] * ND;
          #pragma unroll
          for (int ks = 0; ks < 4; ++ks)
            bfr[ks] = *(const bf16x8*)(src + ks * 32 + lg * 8);
        } else {
          #pragma unroll
          for (int ks = 0; ks < 4; ++ks) bfr[ks] = (bf16x8)0;
        }
        f32x4 acc;
        #pragma unroll
        for (int r = 0; r < 4; ++r) acc[r] = 0.f;
        #pragma unroll
        for (int ks = 0; ks < 4; ++ks)
          acc = __builtin_amdgcn_mfma_f32_16x16x32_bf16(af[ks], bfr[ks], acc, 0, 0, 0);

        #pragma unroll
        for (int r = 0; r < 4; ++r) {
          const int R = rb * 16 + lg * 4 + r;
          const int Cj = cb * 16 + lr_;
          const bool ok = (R < c) && (Cj < c) && (R != Cj);
          const float sv = acc[r];
          float xn = fmaf(sv * sv, G2, NEG_C);
          xn = (sv > -0.25f) ? xn : 0.f;
          corr[r] += ok ? fexp2(xn) : 0.f;
          if (ok) {
            const float t1 = 1.25f - sv;
            const float xp = G2 * fmaxf(t1, 0.f) * (t1 - 0.5f);
            if (xp > mp[r]) { sp[r] = sp[r] * fexp2(mp[r] - xp) + 1.f; mp[r] = xp; }
            else sp[r] += fexp2(xp - mp[r]);
          }
        }
      }
      #pragma unroll
      for (int r = 0; r < 4; ++r) {
        #pragma unroll
        for (int off = 1; off < 16; off <<= 1) {
          corr[r] += __shfl_xor(corr[r], off);
          const float m2 = __shfl_xor(mp[r], off), s2 = __shfl_xor(sp[r], off);
          const float M = fmaxf(mp[r], m2);
          const float t1 = sp[r] * fexp2(mp[r] - M);  // exp2(-1e30)=0 for empties
          const float t2 = s2 * fexp2(m2 - M);
          mp[r] = M; sp[r] = t1 + t2;
        }
      }
      if (lr_ == 0) {
        #pragma unroll
        for (int r = 0; r < 4; ++r) {
          const int R = rb * 16 + lg * 4 + r;
          if (R < c) {
            float* o = poscorr + (size_t)memL[R] * 4;
            o[0] = mp[r]; o[1] = sp[r]; o[2] = corr[r]; o[3] = (float)(c - 1);
          }
        }
      }
    }
  }
}

// ---- k3: per-row finish + fused final scalar via arrival counter ----------
__global__ __launch_bounds__(256) void k_rowsfinal(const float* __restrict__ part,
                                                   const float* __restrict__ poscorr,
                                                   float* __restrict__ bsum,
                                                   int* __restrict__ counter,
                                                   float* __restrict__ out) {
  const int bid = blockIdx.x;
  const int tid = threadIdx.x;
  const int l = tid & 63, w = tid >> 6;
  const int row = bid * 256 + tid;
  float sn = 0.f;
  #pragma unroll 8
  for (int q = 0; q < NT; ++q)
    sn += part[(size_t)q * NB + row];    // coalesced: 256 consecutive floats/q
  const float4 pc = *reinterpret_cast<const float4*>(poscorr + (size_t)row * 4);
  const int npi = (int)(pc.w + 0.5f);
  const bool valid = (npi > 0) && (npi < NB - 1);
  float val = 0.f;
  if (valid) {
    const float snn = fmaxf(sn - pc.z, 1e-30f);
    const float lp = LN2F * (pc.x + log2f(pc.y));
    const float ln_ = LN2F * log2f(snn);
    const float x = lp + ln_;
    val = fmaxf(x, 0.f) + log1pf(expf(-fabsf(x)));  // stable softplus
  }
  float cnt = valid ? 1.f : 0.f;
  val = wave_sum_f(val);
  cnt = wave_sum_f(cnt);
  __shared__ float svals[4], scnts[4];
  __shared__ int lastflag;
  if (l == 0) { svals[w] = val; scnts[w] = cnt; }
  __syncthreads();
  if (tid == 0) {
    bsum[bid * 2 + 0] = svals[0] + svals[1] + svals[2] + svals[3];
    bsum[bid * 2 + 1] = scnts[0] + scnts[1] + scnts[2] + scnts[3];
    __threadfence();                       // publish bsum device-wide
    const int prev = atomicAdd(counter, 1);
    lastflag = (prev == 31);
  }
  __syncthreads();
  if (lastflag && w == 0) {
    __threadfence();                       // acquire all blocks' bsum
    float s = 0.f, c = 0.f;
    if (l < 32) {
      volatile const float* vb = (volatile const float*)bsum;
      s = vb[l * 2];
      c = vb[l * 2 + 1];
    }
    s = wave_sum_f(s);
    c = wave_sum_f(c);
    if (l == 0) out[0] = s / fmaxf(c, 1.f);
  }
}

extern "C" void kernel_launch(void* const* d_in, const int* in_sizes, int n_in,
                              void* d_out, int out_size, void* d_ws, size_t ws_size,
                              hipStream_t stream) {
  const float* emb = (const float*)d_in[0];
  const int* labels = (const int*)d_in[1];
  float* out = (float*)d_out;
  char* ws = (char*)d_ws;

  float* part    = (float*)(ws + 0);         // 64*8192*4  = 2097152
  float* poscorr = (float*)(ws + 2097152);   // 8192*4*4   = 131072
  u16*   ebf     = (u16*)  (ws + 2228224);   // 8192*128*2 = 2097152
  float* bsum    = (float*)(ws + 4325376);   // 256 B
  int*   counter = (int*)  (ws + 4325632);   // 8 B

  k_prep<<<NB / 8, 512, 0, stream>>>(emb, ebf, counter);
  k_mainpos<<<NTRI + NLAB / 4, 256, 0, stream>>>(ebf, labels, part, poscorr);
  k_rowsfinal<<<NB / 256, 256, 0, stream>>>(part, poscorr, bsum, counter, out);
}